// Round 10
// baseline (349.427 us; speedup 1.0000x reference)
//
#include <hip/hip_runtime.h>
#include <hip/hip_bf16.h>
#include <hip/hip_fp16.h>

#define NN 50000      // nodes
#define NE 1600000    // edges
#define DD 128        // channels
#define HH 4          // heads
#define BSH2 5        // bucket shift: 32 nodes per bucket
#define NBKT2 1563    // ceil(NN / 32)
#define NBP2 2048     // padded bucket count
#define CAP 1408      // padded edges per bucket (mean 1024, +12 sigma)
#define PCHUNK 2048   // edges per partition block
#define NPB 782       // ceil(NE / PCHUNK)
#define GEMMB 782     // gemm blocks (3125 tiles / 4 waves)

typedef __attribute__((ext_vector_type(8))) short short8;
typedef __attribute__((ext_vector_type(4))) float floatx4;
typedef __attribute__((ext_vector_type(2))) _Float16 h2;

__device__ inline h2 as_h2(unsigned u) {
    union { unsigned u; h2 h; } c; c.u = u; return c.h;
}

__device__ inline float dot4(h2 a01, h2 a23, h2 b01, h2 b23) {
#if defined(__has_builtin) && __has_builtin(__builtin_amdgcn_fdot2)
    return __builtin_amdgcn_fdot2(a01, b01, __builtin_amdgcn_fdot2(a23, b23, 0.f, false), false);
#else
    return (float)a01.x * (float)b01.x + (float)a01.y * (float)b01.y +
           (float)a23.x * (float)b23.x + (float)a23.y * (float)b23.y;
#endif
}

// ---------------- prep: split fp32 W -> bf16 hi/lo + zero bucket cursors ----------------
__global__ __launch_bounds__(256) void prep_w(
    const float* __restrict__ Wk, const float* __restrict__ Wq, const float* __restrict__ Wv,
    unsigned short* __restrict__ hi, unsigned short* __restrict__ lo, int* __restrict__ bcur)
{
    int j = blockIdx.x * 256 + threadIdx.x;
    if (j < NBP2) bcur[j] = 0;
    if (j >= 3 * DD * DD) return;
    int which = j / (DD * DD);
    int off = j - which * (DD * DD);
    const float* W = (which == 0) ? Wk : (which == 1) ? Wq : Wv;
    float w = W[off];
    unsigned int b = __float_as_uint(w);
    unsigned short h = (unsigned short)(b >> 16);
    float hf = __uint_as_float((unsigned int)h << 16);
    float l = w - hf;
    hi[j] = h;
    lo[j] = (unsigned short)(__float_as_uint(l) >> 16);
}

// ---------------- partition: bucket-window scatter (standalone, high-occupancy) ----------------
__global__ __launch_bounds__(256) void partition(
    const int* __restrict__ src, const int* __restrict__ dst,
    int* __restrict__ bcur, int* __restrict__ epack)
{
    __shared__ int h[NBP2];
    __shared__ int c2[NBP2];
    int b0 = blockIdx.x * PCHUNK;
    int n = min(PCHUNK, NE - b0);
    for (int i = threadIdx.x; i < NBP2; i += 256) h[i] = 0;
    __syncthreads();
    for (int i = threadIdx.x; i < n; i += 256)
        atomicAdd(&h[dst[b0 + i] >> BSH2], 1);
    __syncthreads();
    for (int i = threadIdx.x; i < NBP2; i += 256)
        c2[i] = h[i] ? i * CAP + atomicAdd(&bcur[i], h[i]) : 0;
    __syncthreads();
    for (int i = threadIdx.x; i < n; i += 256) {
        int d = dst[b0 + i];
        int s = src[b0 + i];
        int bkt = d >> BSH2;
        int pos = atomicAdd(&c2[bkt], 1);
        if (pos < (bkt + 1) * CAP)               // drop-guard (never fires at +12 sigma)
            epack[pos] = ((d & 31) << 16) | s;
    }
}

// ---------------- fused QKV projection GEMM (split bf16 MFMA), LDS-staged epilogue ----------------
__global__ __launch_bounds__(256) void gemm_qkv(
    const float* __restrict__ x,
    const unsigned short* __restrict__ whi, const unsigned short* __restrict__ wlo,
    const float* __restrict__ bk, const float* __restrict__ bq, const float* __restrict__ bv,
    uint4* __restrict__ kvpack, __half* __restrict__ qh)
{
    __shared__ __align__(16) unsigned short stage[4][4096];   // 8 KB per wave
    int wave = threadIdx.x >> 6;
    int tile = blockIdx.x * 4 + wave;
    int n0 = tile * 16;
    if (n0 >= NN) return;
    int lane = threadIdx.x & 63;
    int m    = lane & 15;
    int quad = lane >> 4;

    const float* xrow = x + (size_t)(n0 + m) * DD + quad * 8;
    short8 ah[4], al[4];
#pragma unroll
    for (int ks = 0; ks < 4; ++ks) {
        const float* xr = xrow + ks * 32;
        float4 t0 = *(const float4*)xr;
        float4 t1 = *(const float4*)(xr + 4);
        float xv[8] = {t0.x, t0.y, t0.z, t0.w, t1.x, t1.y, t1.z, t1.w};
#pragma unroll
        for (int j = 0; j < 8; ++j) {
            unsigned int b = __float_as_uint(xv[j]);
            unsigned short h = (unsigned short)(b >> 16);
            float hf = __uint_as_float((unsigned int)h << 16);
            float l = xv[j] - hf;
            ah[ks][j] = (short)h;
            al[ks][j] = (short)(__float_as_uint(l) >> 16);
        }
    }

    floatx4 acc[3][8];
#pragma unroll
    for (int p = 0; p < 3; ++p)
#pragma unroll
        for (int ct = 0; ct < 8; ++ct)
            acc[p][ct] = (floatx4){0.f, 0.f, 0.f, 0.f};

#pragma unroll
    for (int ks = 0; ks < 4; ++ks) {
#pragma unroll
        for (int p = 0; p < 3; ++p) {
            size_t base = (size_t)p * DD * DD + (size_t)m * DD + ks * 32 + quad * 8;
#pragma unroll
            for (int ct = 0; ct < 8; ++ct) {
                size_t o = base + (size_t)ct * 16 * DD;
                short8 bh = *(const short8*)(whi + o);
                short8 bl = *(const short8*)(wlo + o);
                acc[p][ct] = __builtin_amdgcn_mfma_f32_16x16x32_bf16(ah[ks], bh, acc[p][ct], 0, 0, 0);
                acc[p][ct] = __builtin_amdgcn_mfma_f32_16x16x32_bf16(ah[ks], bl, acc[p][ct], 0, 0, 0);
                acc[p][ct] = __builtin_amdgcn_mfma_f32_16x16x32_bf16(al[ks], bh, acc[p][ct], 0, 0, 0);
            }
        }
    }

    int col = lane & 15;
    unsigned short* st = stage[wave];
    uint4* st4 = (uint4*)st;

    // kv: stage packed {k4,v4} per 4-ch group, then coalesced uint4 stores
#pragma unroll
    for (int ct = 0; ct < 8; ++ct) {
        int j = ct * 16 + col;
        int g = j >> 2, slot = j & 3;
        float biask = bk[j], biasv = bv[j];
#pragma unroll
        for (int r = 0; r < 4; ++r) {
            int row = quad * 4 + r;
            st[row * 256 + g * 8 + slot]     = __half_as_ushort(__float2half(acc[0][ct][r] + biask));
            st[row * 256 + g * 8 + 4 + slot] = __half_as_ushort(__float2half(acc[2][ct][r] + biasv));
        }
    }
#pragma unroll
    for (int t = 0; t < 8; ++t) {
        int flat = t * 64 + lane;
        kvpack[((size_t)n0 + (flat >> 5)) * 32 + (flat & 31)] = st4[flat];
    }

    // q: stage row-major fp16, then coalesced uint4 stores
#pragma unroll
    for (int ct = 0; ct < 8; ++ct) {
        int j = ct * 16 + col;
        float biasq = bq[j];
#pragma unroll
        for (int r = 0; r < 4; ++r) {
            int row = quad * 4 + r;
            st[row * 128 + j] = __half_as_ushort(__float2half(acc[1][ct][r] + biasq));
        }
    }
#pragma unroll
    for (int t = 0; t < 4; ++t) {
        int flat = t * 64 + lane;
        ((uint4*)qh)[((size_t)n0 + (flat >> 4)) * 16 + (flat & 15)] = st4[flat];
    }
}

// ---------------- fused per-bucket GAT: LDS CSR + scores + online softmax + aggregate ----------------
// One 256-thread block per 32-node bucket; half-wave (32 lanes) per node. Register
// double-buffer (kva/kvb) pipelines the next 8 kv-row gathers under the softmax update.
__global__ __launch_bounds__(256) void gat_bucket(
    const __half* __restrict__ qh, const uint4* __restrict__ kvpack,
    const int* __restrict__ epack, const int* __restrict__ bcur,
    float* __restrict__ out)
{
    __shared__ int hist[32];
    __shared__ int cur[32];
    __shared__ int begs[33];
    __shared__ unsigned short els[CAP];
    int b = blockIdx.x;
    int cnt = min(bcur[b], CAP);
    int base = b * CAP;
    int n0 = b << BSH2;
    int nnodes = min(32, NN - n0);
    int tid = threadIdx.x;

    if (tid < 32) hist[tid] = 0;
    __syncthreads();
    for (int e = tid; e < cnt; e += 256)
        atomicAdd(&hist[epack[base + e] >> 16], 1);
    __syncthreads();
    if (tid < 32) {                        // lanes 0..31 of wave 0: exclusive scan of 32 bins
        int c = hist[tid], inc = c;
#pragma unroll
        for (int d = 1; d < 32; d <<= 1) {
            int t = __shfl_up(inc, d);
            if (tid >= d) inc += t;
        }
        int excl = inc - c;
        begs[tid] = excl;
        cur[tid]  = excl;
        if (tid == 31) begs[32] = excl + c;
    }
    __syncthreads();
    for (int e = tid; e < cnt; e += 256) {
        int p = epack[base + e];
        int pos = atomicAdd(&cur[p >> 16], 1);
        els[pos] = (unsigned short)(p & 0xFFFF);
    }
    __syncthreads();

    int il = tid & 31;
    int hw = tid >> 5;                     // half-wave id: 0..7

    for (int nl = hw; nl < nnodes; nl += 8) {
        int node = n0 + nl;
        int beg = begs[nl], end = begs[nl + 1];

        uint2 qq = *(const uint2*)(qh + (size_t)node * 128 + il * 4);
        h2 qh01 = as_h2(qq.x), qh23 = as_h2(qq.y);

        float m = -INFINITY, ssum = 0.f;
        float o0 = 0.f, o1 = 0.f, o2 = 0.f, o3 = 0.f;

        uint4 kva[8], kvb[8];

        auto loadb = [&](uint4* kv, int j) {
            int nh = min(8, end - j);
#pragma unroll
            for (int i = 0; i < 8; ++i) {
                int s = els[j + ((i < nh) ? i : 0)];
                kv[i] = kvpack[(size_t)s * 32 + il];
            }
        };
        auto computeb = [&](const uint4* kv, int j) {
            int nh = min(8, end - j);
            float p[8];
#pragma unroll
            for (int i = 0; i < 8; ++i) {
                float t = dot4(as_h2(kv[i].x), as_h2(kv[i].y), qh01, qh23);
                t += __shfl_xor(t, 1);
                t += __shfl_xor(t, 2);
                t += __shfl_xor(t, 4);
                p[i] = (i < nh) ? t : -INFINITY;
            }
            float gm = fmaxf(fmaxf(fmaxf(p[0], p[1]), fmaxf(p[2], p[3])),
                             fmaxf(fmaxf(p[4], p[5]), fmaxf(p[6], p[7])));
            float nm = fmaxf(m, gm);
            float nmc = fmaxf(nm, -1e30f);
            float scale = __expf(m - nmc);
            ssum *= scale; o0 *= scale; o1 *= scale; o2 *= scale; o3 *= scale;
#pragma unroll
            for (int i = 0; i < 8; ++i) {
                float w = __expf(p[i] - nmc);
                ssum += w;
                o0 += w * (float)as_h2(kv[i].z).x;
                o1 += w * (float)as_h2(kv[i].z).y;
                o2 += w * (float)as_h2(kv[i].w).x;
                o3 += w * (float)as_h2(kv[i].w).y;
            }
            m = nm;
        };

        if (beg < end) {
            int j = beg;
            loadb(kva, j);
            for (;;) {
                int jn = j + 8;
                if (jn < end) loadb(kvb, jn);      // prefetch next batch
                computeb(kva, j);
                j = jn;
                if (j >= end) break;
                jn = j + 8;
                if (jn < end) loadb(kva, jn);      // prefetch next batch
                computeb(kvb, j);
                j = jn;
                if (j >= end) break;
            }
        }

        float invd = (ssum > 0.f) ? 1.f / ssum : 0.f;
        float4 r = {o0 * invd, o1 * invd, o2 * invd, o3 * invd};
        *(float4*)(out + (size_t)node * DD + il * 4) = r;
    }
}

extern "C" void kernel_launch(void* const* d_in, const int* in_sizes, int n_in,
                              void* d_out, int out_size, void* d_ws, size_t ws_size,
                              hipStream_t stream) {
    const float* x  = (const float*)d_in[0];
    const float* Wk = (const float*)d_in[1];
    const float* bk = (const float*)d_in[2];
    const float* Wq = (const float*)d_in[3];
    const float* bq = (const float*)d_in[4];
    const float* Wv = (const float*)d_in[5];
    const float* bv = (const float*)d_in[6];
    const int* src = (const int*)d_in[7];
    const int* dst = (const int*)d_in[8];

    // workspace layout (16B-aligned first)
    uint4*  kvpack = (uint4*)d_ws;                                 // NN*32 uint4 (512B/node)
    __half* qh     = (__half*)(kvpack + (size_t)NN * 32);          // NN*DD fp16
    unsigned short* whi = (unsigned short*)(qh + (size_t)NN * DD); // 3*DD*DD
    unsigned short* wlo = whi + (size_t)3 * DD * DD;               // 3*DD*DD
    int* epack = (int*)(wlo + (size_t)3 * DD * DD);                // NBKT2*CAP (padded windows)
    int* bcur  = epack + (size_t)NBKT2 * CAP;                      // NBP2

    prep_w<<<(3 * DD * DD + 255) / 256, 256, 0, stream>>>(Wk, Wq, Wv, whi, wlo, bcur);
    partition<<<NPB, 256, 0, stream>>>(src, dst, bcur, epack);
    gemm_qkv<<<GEMMB, 256, 0, stream>>>(x, whi, wlo, bk, bq, bv, kvpack, qh);
    gat_bucket<<<NBKT2, 256, 0, stream>>>(qh, kvpack, epack, bcur, (float*)d_out);
}